// Round 10
// baseline (441.566 us; speedup 1.0000x reference)
//
#include <hip/hip_runtime.h>
#include <hip/hip_bf16.h>

#define T_DIM 2048
#define B_DIM 32
#define CIN   80
#define H_DIM 256
#define TT    16               // t-tile per conv block
#define NTB   (T_DIM / TT)     // 128
#define NBLK  (B_DIM * NTB)    // 4096 conv blocks
#define KTOT  (CIN * 3)        // 240
#define NKK   (KTOT / 4)       // 60 MFMA K-steps

// LIF chunking (warm-up resync; verified absmax=0 in R3-R9)
#define CHUNKS 32
#define CLEN  (T_DIM / CHUNKS) // 64
#define WARM  48
#define SEG   8                // timesteps per LDS staging segment (32 KB dbuf)

#define NPART 64
#define JPER  (NBLK / NPART)   // 64
#define NPY   256              // from-Y stats partials (fallback mode)
#define TPY   (T_DIM / NPY)    // 8

typedef unsigned short u16;
typedef __attribute__((ext_vector_type(4))) double d4;

// ---- workspace byte offsets ----
// flag[0]=isbf, flag[1]=mfma combo id (-1 = VALU fallback), flag[2]=stats-from-Y mode
#define PS_OFF  ((size_t)64)
#define PQ_OFF  (PS_OFF + (size_t)NBLK * H_DIM * 8)
#define PAR_OFF (PQ_OFF + (size_t)NBLK * H_DIM * 8)
#define WT_OFF  (PAR_OFF + (size_t)768 * 8)
#define PA_OFF  WT_OFF                                  // alias WT (dead after conv)
#define PB_OFF  (WT_OFF + (size_t)NPART * H_DIM * 8)
#define Y_OFF   (WT_OFF + (size_t)H_DIM * CIN * 3 * 8)
#define Y_ELEMS ((size_t)T_DIM * B_DIM * H_DIM)         // 16,777,216

__device__ __forceinline__ double bf2d(u16 u) {
    union { unsigned int i; float f; } cv;
    cv.i = ((unsigned int)u) << 16;
    return (double)cv.f;
}

__device__ __forceinline__ double ld_in(const void* p, int i, int isbf) {
    if (isbf) return bf2d(((const u16*)p)[i]);
    return (double)((const float*)p)[i];
}

// candidate lane->fragment index maps
__device__ __forceinline__ void combo_maps(int combo, int l,
                                           int& ai, int& ak, int& bk, int& bj,
                                           int di[4], int dj[4]) {
    if (combo & 1) { ai = l >> 2; ak = l & 3; } else { ai = l & 15; ak = l >> 4; }
    if (combo & 2) { bk = l & 3; bj = l >> 2; } else { bk = l >> 4; bj = l & 15; }
    const int dc = (combo >> 2) & 3;
#pragma unroll
    for (int r = 0; r < 4; r++) {
        if (dc == 0)      { di[r] = 4 * (l >> 4) + r; dj[r] = l & 15; }
        else if (dc == 1) { di[r] = (l >> 4) + 4 * r; dj[r] = l & 15; }
        else if (dc == 2) { di[r] = l & 15; dj[r] = 4 * (l >> 4) + r; }
        else              { di[r] = l & 15; dj[r] = (l >> 4) + 4 * r; }
    }
}

// ---- kernel 0 (merged prep): per-block dtype detect + w transpose + (block 240) mfma layout probe ----
__global__ __launch_bounds__(256) void k_prep(const u16* __restrict__ xu,
                                              const void* __restrict__ w,
                                              int* __restrict__ flag,
                                              double* __restrict__ wt) {
    __shared__ int cnt[256];
    __shared__ int isbf_s;
    const int tid = threadIdx.x;
    int c = 0;
    for (int j = 0; j < 8; j++) {
        u16 u = xu[tid * 8 + j];
        int e = (u >> 7) & 0xFF;
        if ((u & 0x7FFF) == 0 || (e >= 97 && e <= 157)) c++;
    }
    cnt[tid] = c;
    __syncthreads();
    for (int off = 128; off > 0; off >>= 1) {
        if (tid < off) cnt[tid] += cnt[tid + off];
        __syncthreads();
    }
    if (tid == 0) isbf_s = (cnt[0] >= 1639) ? 1 : 0;
    __syncthreads();
    const int isbf = isbf_s;

    if (blockIdx.x < 240) {
        int idx = blockIdx.x * 256 + tid;        // < 61440 = H*CIN*3
        int h = idx / KTOT;
        int r = idx - h * KTOT;
        wt[(size_t)r * H_DIM + h] = ld_in(w, idx, isbf);
    } else {
        if (tid < 64) {
            const int l = tid;
            int found = -1;
            for (int combo = 0; combo < 16; combo++) {
                int ai, ak, bk, bj, di[4], dj[4];
                combo_maps(combo, l, ai, ak, bk, bj, di, dj);
                double a = (double)(ai * 4 + ak + 1);
                double b = (double)(bk * 16 + bj + 1);
                d4 cc;
#pragma unroll
                for (int r = 0; r < 4; r++) cc[r] = (double)(di[r] * 16 + dj[r]);
                d4 d = __builtin_amdgcn_mfma_f64_16x16x4f64(a, b, cc, 0, 0, 0);
                bool ok = true;
#pragma unroll
                for (int r = 0; r < 4; r++) {
                    double ref = (double)(di[r] * 16 + dj[r]);
                    for (int k = 0; k < 4; k++)
                        ref += (double)(di[r] * 4 + k + 1) * (double)(k * 16 + dj[r] + 1);
                    if (d[r] != ref) ok = false;
                }
                if (__all(ok) && found < 0) found = combo;
            }
            if (l == 0) {
                flag[1] = found;
                flag[2] = (found >= 0 && ((found >> 2) & 3) >= 2) ? 1 : 0;
            }
        }
        if (tid == 0) flag[0] = isbf;
    }
}

// ---- kernel 2: conv1d as f64 GEMM; depth-2 prefetch MFMA + fused BN partials ----
template <typename YT>
__global__ __launch_bounds__(256, 4) void k_conv2(const void* __restrict__ x,
                                                  const void* __restrict__ bias,
                                                  const int* __restrict__ flag,
                                                  const double* __restrict__ wt,
                                                  YT* __restrict__ y,
                                                  double* __restrict__ ps,
                                                  double* __restrict__ pq) {
    __shared__ __align__(16) double xs[CIN * (TT + 2)];  // xs[ci*18 + tl], tl0 = t0-1
    const int isbf = flag[0];
    const int tb = blockIdx.x;
    const int b  = blockIdx.y;
    const int t0 = tb * TT;

    for (int idx = threadIdx.x; idx < CIN * (TT + 2); idx += 256) {
        int tl = idx / CIN;
        int ci = idx - tl * CIN;
        int tg = t0 - 1 + tl;
        double v = 0.0;
        if (tg >= 0 && tg < T_DIM) v = ld_in(x, (b * T_DIM + tg) * CIN + ci, isbf);
        xs[ci * (TT + 2) + tl] = v;
    }
    __syncthreads();

    const int combo = flag[1];
    const int blk = b * NTB + tb;
    const int h = threadIdx.x;

    if (combo >= 0) {
        // ---------- MFMA path: D[t][h] = sum_k A[t][k]*B[k][h] ----------
        const int wave = threadIdx.x >> 6;
        const int lane = threadIdx.x & 63;
        const int h0w  = wave * 64;
        int ai, ak, bk, bj, di[4], dj[4];
        combo_maps(combo, lane, ai, ak, bk, bj, di, dj);

        d4 acc[4];
#pragma unroll
        for (int ht = 0; ht < 4; ht++) { acc[ht][0] = 0.0; acc[ht][1] = 0.0; acc[ht][2] = 0.0; acc[ht][3] = 0.0; }

        // depth-2 software pipeline on A (LDS) and B (global/L2) operands
        double aq[2];
        double bq[2][4];
#pragma unroll
        for (int s = 0; s < 2; s++) {
            const int ka = s * 4 + ak;
            const int ca = ka / 3, da = ka - 3 * ca;
            aq[s] = xs[ca * (TT + 2) + ai + da];
            const double* wr = wt + (size_t)(s * 4 + bk) * H_DIM + h0w + bj;
#pragma unroll
            for (int ht = 0; ht < 4; ht++) bq[s][ht] = wr[ht * 16];
        }

        for (int kk = 0; kk < NKK; kk++) {
            const int st = kk & 1;
            const double a_c = aq[st];
            double b_c[4];
#pragma unroll
            for (int ht = 0; ht < 4; ht++) b_c[ht] = bq[st][ht];
            if (kk + 2 < NKK) {          // refill stage st for kk+2 (issues early)
                const int ka = (kk + 2) * 4 + ak;
                const int ca = ka / 3, da = ka - 3 * ca;
                aq[st] = xs[ca * (TT + 2) + ai + da];
                const double* wr = wt + (size_t)((kk + 2) * 4 + bk) * H_DIM + h0w + bj;
#pragma unroll
                for (int ht = 0; ht < 4; ht++) bq[st][ht] = wr[ht * 16];
            }
#pragma unroll
            for (int ht = 0; ht < 4; ht++)
                acc[ht] = __builtin_amdgcn_mfma_f64_16x16x4f64(a_c, b_c[ht], acc[ht], 0, 0, 0);
        }

        // ---------- epilogue: bias + direct Y stores + fused BN partials ----------
        const int dc = (combo >> 2) & 3;
        if (dc < 2) {
            // dj[r] = lane&15 (constant per lane) -> per-h bias & shuffle reduction
#pragma unroll
            for (int ht = 0; ht < 4; ht++) {
                const double bv = ld_in(bias, h0w + ht * 16 + (lane & 15), isbf);
                double s1 = 0.0, s2 = 0.0;
#pragma unroll
                for (int r = 0; r < 4; r++) {
                    double v = acc[ht][r] + bv;
                    y[((size_t)(t0 + di[r]) * B_DIM + b) * H_DIM + h0w + ht * 16 + dj[r]] = (YT)v;
                    s1 += v;
                    s2 = fma(v, v, s2);
                }
                // combine the 4 t-row groups (lanes differing in bits 4-5)
                s1 += __shfl_xor(s1, 16); s1 += __shfl_xor(s1, 32);
                s2 += __shfl_xor(s2, 16); s2 += __shfl_xor(s2, 32);
                if ((lane >> 4) == 0) {
                    ps[(size_t)blk * H_DIM + h0w + ht * 16 + lane] = s1;
                    pq[(size_t)blk * H_DIM + h0w + ht * 16 + lane] = s2;
                }
            }
        } else {
            // rare layout: store Y only; stats computed from Y (flag[2]=1)
#pragma unroll
            for (int ht = 0; ht < 4; ht++)
#pragma unroll
                for (int r = 0; r < 4; r++) {
                    const int hh = h0w + ht * 16 + dj[r];
                    double v = acc[ht][r] + ld_in(bias, hh, isbf);
                    y[((size_t)(t0 + di[r]) * B_DIM + b) * H_DIM + hh] = (YT)v;
                }
        }
    } else {
        // ---------- fallback: R5's LDS-staged VALU conv ----------
        double acc[TT];
        const double bv = ld_in(bias, h, isbf);
#pragma unroll
        for (int i = 0; i < TT; i++) acc[i] = bv;

        const double* wp = wt + h;
        double w0 = wp[0], w1 = wp[H_DIM], w2 = wp[2 * H_DIM];
        for (int ci = 0; ci < CIN; ci++) {
            double wn0 = 0.0, wn1 = 0.0, wn2 = 0.0;
            if (ci + 1 < CIN) {
                const double* wq = wt + (size_t)(ci + 1) * 3 * H_DIM + h;
                wn0 = wq[0]; wn1 = wq[H_DIM]; wn2 = wq[2 * H_DIM];
            }
            const double* xr = xs + ci * (TT + 2);
            double x0 = xr[0], x1 = xr[1];
#pragma unroll
            for (int tt = 0; tt < TT; tt += 2) {
                double2 xp = *(const double2*)(xr + tt + 2);
                acc[tt]     = fma(w2, xp.x, fma(w1, x1,   fma(w0, x0, acc[tt])));
                acc[tt + 1] = fma(w2, xp.y, fma(w1, xp.x, fma(w0, x1, acc[tt + 1])));
                x0 = xp.x; x1 = xp.y;
            }
            w0 = wn0; w1 = wn1; w2 = wn2;
        }

        double s1 = 0.0, s2 = 0.0;
#pragma unroll
        for (int tt = 0; tt < TT; tt++) {
            y[((size_t)(t0 + tt) * B_DIM + b) * H_DIM + h] = (YT)acc[tt];
            s1 += acc[tt];
            s2 = fma(acc[tt], acc[tt], s2);
        }
        ps[(size_t)blk * H_DIM + h] = s1;
        pq[(size_t)blk * H_DIM + h] = s2;
    }
}

// ---- kernel 3a: partial BN reduce (mode 0: PS/PQ; mode 1: from Y) ----
template <typename YT>
__global__ __launch_bounds__(256) void k_statsA(const YT* __restrict__ y,
                                                double* __restrict__ ps,
                                                double* __restrict__ pq,
                                                double* __restrict__ pa,
                                                double* __restrict__ pb,
                                                const int* __restrict__ flag) {
    const int h = threadIdx.x;
    if (flag[2]) {
        const int p = blockIdx.x;            // 0..255, each covers TPY t-values
        const int tp0 = p * TPY;
        double s1 = 0.0, s2 = 0.0;
        for (int row = 0; row < TPY * B_DIM; row++) {
            int t = tp0 + (row >> 5);
            int bb = row & 31;
            double v = (double)y[((size_t)t * B_DIM + bb) * H_DIM + h];
            s1 += v;
            s2 = fma(v, v, s2);
        }
        ps[(size_t)p * H_DIM + h] = s1;
        pq[(size_t)p * H_DIM + h] = s2;
    } else {
        if (blockIdx.x >= NPART) return;
        const int k = blockIdx.x;
        double s1 = 0.0, s2 = 0.0;
        const int j0 = k * JPER;
        for (int j = j0; j < j0 + JPER; j++) {
            s1 += ps[(size_t)j * H_DIM + h];
            s2 += pq[(size_t)j * H_DIM + h];
        }
        pa[(size_t)k * H_DIM + h] = s1;
        pb[(size_t)k * H_DIM + h] = s2;
    }
}

// ---- kernel 3b: final reduce + fold BN affine ----
__global__ __launch_bounds__(256) void k_statsB(const double* __restrict__ ps,
                                                const double* __restrict__ pq,
                                                const double* __restrict__ pa,
                                                const double* __restrict__ pb,
                                                const void* __restrict__ gamma,
                                                const void* __restrict__ beta,
                                                const int* __restrict__ flag,
                                                double* __restrict__ par) {
    const int isbf = flag[0];
    const int h = threadIdx.x;
    double s1 = 0.0, s2 = 0.0;
    if (flag[2]) {
        for (int k = 0; k < NPY; k++) {
            s1 += ps[(size_t)k * H_DIM + h];
            s2 += pq[(size_t)k * H_DIM + h];
        }
    } else {
        for (int k = 0; k < NPART; k++) {
            s1 += pa[(size_t)k * H_DIM + h];
            s2 += pb[(size_t)k * H_DIM + h];
        }
    }
    const double N = (double)T_DIM * (double)B_DIM;
    double mean = s1 / N;
    double var  = s2 / N - mean * mean;
    double r    = 1.0 / sqrt(var + 1e-5);
    par[h]       = mean;
    par[256 + h] = r * ld_in(gamma, h, isbf);
    par[512 + h] = ld_in(beta, h, isbf);
}

// ---- kernel 4: chunked LIF, LDS double-buffered segments (R9 config) ----
template <typename YT>
__global__ __launch_bounds__(256, 4) void k_lif(const YT* __restrict__ y,
                                                const double* __restrict__ par,
                                                const int* __restrict__ flag,
                                                void* __restrict__ out) {
    __shared__ YT buf[2][SEG * H_DIM];   // 2 x 16 KB (f64)
    const int isbf = flag[0];
    const int c = blockIdx.x, b = blockIdx.y, h = threadIdx.x;
    const int t_out = c * CLEN;
    int t_begin = t_out - WARM; if (t_begin < 0) t_begin = 0;
    const int t_end = t_out + CLEN;
    const int nseg = (t_end - t_begin) / SEG;   // 8 (chunk 0) or 14

    const double m  = par[h];
    const double A  = par[256 + h];
    const double be = par[512 + h];

    const size_t ST = (size_t)B_DIM * H_DIM;
    const YT* yb = y + (size_t)b * H_DIM + h;
    u16*   ob16 = (u16*)out + (size_t)b * H_DIM + h;
    float* ob32 = (float*)out + (size_t)b * H_DIM + h;

    {
        YT g[SEG];
#pragma unroll
        for (int k = 0; k < SEG; k++) g[k] = yb[(size_t)(t_begin + k) * ST];
#pragma unroll
        for (int k = 0; k < SEG; k++) buf[0][k * H_DIM + h] = g[k];
    }
    __syncthreads();

    double v = 0.0;
    for (int s = 0; s < nseg; s++) {
        const int cur = s & 1;
        const bool more = (s + 1 < nseg);
        YT g[SEG];
        if (more) {
            const int t1 = t_begin + (s + 1) * SEG;
#pragma unroll
            for (int k = 0; k < SEG; k++) g[k] = yb[(size_t)(t1 + k) * ST];
        }
        double r[SEG];
#pragma unroll
        for (int k = 0; k < SEG; k++) r[k] = (double)buf[cur][k * H_DIM + h];
        const int t0s = t_begin + s * SEG;
#pragma unroll
        for (int k = 0; k < SEG; k++) {
            double val = fma(r[k] - m, A, be);
            v = fma(v, 0.5, val);
            bool sp = (v - 1.0) >= 0.0;
            const int t = t0s + k;
            if (t >= t_out) {
                size_t oi = (size_t)t * ST;
                if (isbf) ob16[oi] = sp ? (u16)0x3F80 : (u16)0;
                else      ob32[oi] = sp ? 1.0f : 0.0f;
            }
            v = sp ? 0.0 : v;
        }
        if (more) {
#pragma unroll
            for (int k = 0; k < SEG; k++) buf[cur ^ 1][k * H_DIM + h] = g[k];
        }
        __syncthreads();
    }
}

// ---- diagnostic: ws too small ----
__global__ void k_code(u16* out, float code) {
    if (threadIdx.x == 0 && blockIdx.x == 0) {
        union { unsigned int i; float f; } cv; cv.f = code;
        out[0] = (u16)(cv.i >> 16);
    }
}

extern "C" void kernel_launch(void* const* d_in, const int* in_sizes, int n_in,
                              void* d_out, int out_size, void* d_ws, size_t ws_size,
                              hipStream_t stream) {
    const void* x     = d_in[0];
    const void* w     = d_in[1];
    const void* cb    = d_in[2];
    const void* gamma = d_in[3];
    const void* beta  = d_in[4];

    char* wsb   = (char*)d_ws;
    int* flag   = (int*)wsb;
    double* PS  = (double*)(wsb + PS_OFF);
    double* PQ  = (double*)(wsb + PQ_OFF);
    double* PAR = (double*)(wsb + PAR_OFF);
    double* WT  = (double*)(wsb + WT_OFF);
    double* PA  = (double*)(wsb + PA_OFF);
    double* PB  = (double*)(wsb + PB_OFF);
    void* Yp    = (void*)(wsb + Y_OFF);

    const size_t need64 = Y_OFF + Y_ELEMS * 8;   // 143,104,064
    const size_t need32 = Y_OFF + Y_ELEMS * 4;

    if (ws_size < need32) {
        hipMemsetAsync(d_out, 0, (size_t)out_size * 2, stream);
        k_code<<<1, 64, 0, stream>>>((u16*)d_out, 1000.0f);
        return;
    }

    k_prep<<<dim3(241), dim3(256), 0, stream>>>((const u16*)x, w, flag, WT);

    if (ws_size >= need64) {
        k_conv2<double><<<dim3(NTB, B_DIM), dim3(256), 0, stream>>>(
            x, cb, flag, WT, (double*)Yp, PS, PQ);
        k_statsA<double><<<dim3(NPY), dim3(256), 0, stream>>>(
            (const double*)Yp, PS, PQ, PA, PB, flag);
        k_statsB<<<dim3(1), dim3(256), 0, stream>>>(PS, PQ, PA, PB, gamma, beta, flag, PAR);
        k_lif<double><<<dim3(CHUNKS, B_DIM), dim3(256), 0, stream>>>(
            (const double*)Yp, PAR, flag, d_out);
    } else {
        k_conv2<float><<<dim3(NTB, B_DIM), dim3(256), 0, stream>>>(
            x, cb, flag, WT, (float*)Yp, PS, PQ);
        k_statsA<float><<<dim3(NPY), dim3(256), 0, stream>>>(
            (const float*)Yp, PS, PQ, PA, PB, flag);
        k_statsB<<<dim3(1), dim3(256), 0, stream>>>(PS, PQ, PA, PB, gamma, beta, flag, PAR);
        k_lif<float><<<dim3(CHUNKS, B_DIM), dim3(256), 0, stream>>>(
            (const float*)Yp, PAR, flag, d_out);
    }
}

// Round 11
// 321.687 us; speedup vs baseline: 1.3727x; 1.3727x over previous
//
#include <hip/hip_runtime.h>
#include <hip/hip_bf16.h>

#define T_DIM 2048
#define B_DIM 32
#define CIN   80
#define H_DIM 256
#define TT    16               // t-tile per conv block
#define NTB   (T_DIM / TT)     // 128
#define NBLK  (B_DIM * NTB)    // 4096 conv blocks
#define KTOT  (CIN * 3)        // 240
#define NKK   (KTOT / 4)       // 60 MFMA K-steps

// LIF chunking (warm-up resync; verified absmax=0 in R3-R10)
#define CHUNKS 32
#define CLEN  (T_DIM / CHUNKS) // 64
#define WARM  48
#define SEG   8                // timesteps per LDS staging segment

#define NPART 64
#define JPER  (NBLK / NPART)   // 64
#define NPY   256              // from-Y stats partials (fallback mode)
#define TPY   (T_DIM / NPY)    // 8

typedef unsigned short u16;
typedef __attribute__((ext_vector_type(4))) double d4;

// ---- workspace byte offsets ----
// flag[0]=isbf, flag[1]=mfma combo id (-1 = VALU fallback), flag[2]=stats-from-Y mode
#define PS_OFF  ((size_t)64)
#define PQ_OFF  (PS_OFF + (size_t)NBLK * H_DIM * 8)
#define PAR_OFF (PQ_OFF + (size_t)NBLK * H_DIM * 8)
#define WT_OFF  (PAR_OFF + (size_t)768 * 8)
#define PA_OFF  WT_OFF                                  // alias WT (dead after conv)
#define PB_OFF  (WT_OFF + (size_t)NPART * H_DIM * 8)
#define Y_OFF   (WT_OFF + (size_t)H_DIM * CIN * 3 * 8)
#define Y_ELEMS ((size_t)T_DIM * B_DIM * H_DIM)         // 16,777,216

__device__ __forceinline__ double bf2d(u16 u) {
    union { unsigned int i; float f; } cv;
    cv.i = ((unsigned int)u) << 16;
    return (double)cv.f;
}

__device__ __forceinline__ double ld_in(const void* p, int i, int isbf) {
    if (isbf) return bf2d(((const u16*)p)[i]);
    return (double)((const float*)p)[i];
}

// candidate lane->fragment index maps
__device__ __forceinline__ void combo_maps(int combo, int l,
                                           int& ai, int& ak, int& bk, int& bj,
                                           int di[4], int dj[4]) {
    if (combo & 1) { ai = l >> 2; ak = l & 3; } else { ai = l & 15; ak = l >> 4; }
    if (combo & 2) { bk = l & 3; bj = l >> 2; } else { bk = l >> 4; bj = l & 15; }
    const int dc = (combo >> 2) & 3;
#pragma unroll
    for (int r = 0; r < 4; r++) {
        if (dc == 0)      { di[r] = 4 * (l >> 4) + r; dj[r] = l & 15; }
        else if (dc == 1) { di[r] = (l >> 4) + 4 * r; dj[r] = l & 15; }
        else if (dc == 2) { di[r] = l & 15; dj[r] = 4 * (l >> 4) + r; }
        else              { di[r] = l & 15; dj[r] = (l >> 4) + 4 * r; }
    }
}

// ---- kernel 0 (merged prep): dtype detect + w transpose + (block 240) layout probe ----
__global__ __launch_bounds__(256) void k_prep(const u16* __restrict__ xu,
                                              const void* __restrict__ w,
                                              int* __restrict__ flag,
                                              double* __restrict__ wt) {
    __shared__ int cnt[256];
    __shared__ int isbf_s;
    const int tid = threadIdx.x;
    int c = 0;
    for (int j = 0; j < 8; j++) {
        u16 u = xu[tid * 8 + j];
        int e = (u >> 7) & 0xFF;
        if ((u & 0x7FFF) == 0 || (e >= 97 && e <= 157)) c++;
    }
    cnt[tid] = c;
    __syncthreads();
    for (int off = 128; off > 0; off >>= 1) {
        if (tid < off) cnt[tid] += cnt[tid + off];
        __syncthreads();
    }
    if (tid == 0) isbf_s = (cnt[0] >= 1639) ? 1 : 0;
    __syncthreads();
    const int isbf = isbf_s;

    if (blockIdx.x < 240) {
        int idx = blockIdx.x * 256 + tid;        // < 61440 = H*CIN*3
        int h = idx / KTOT;
        int r = idx - h * KTOT;
        wt[(size_t)r * H_DIM + h] = ld_in(w, idx, isbf);
    } else {
        if (tid < 64) {
            const int l = tid;
            int found = -1;
            for (int combo = 0; combo < 16; combo++) {
                int ai, ak, bk, bj, di[4], dj[4];
                combo_maps(combo, l, ai, ak, bk, bj, di, dj);
                double a = (double)(ai * 4 + ak + 1);
                double b = (double)(bk * 16 + bj + 1);
                d4 cc;
#pragma unroll
                for (int r = 0; r < 4; r++) cc[r] = (double)(di[r] * 16 + dj[r]);
                d4 d = __builtin_amdgcn_mfma_f64_16x16x4f64(a, b, cc, 0, 0, 0);
                bool ok = true;
#pragma unroll
                for (int r = 0; r < 4; r++) {
                    double ref = (double)(di[r] * 16 + dj[r]);
                    for (int k = 0; k < 4; k++)
                        ref += (double)(di[r] * 4 + k + 1) * (double)(k * 16 + dj[r] + 1);
                    if (d[r] != ref) ok = false;
                }
                if (__all(ok) && found < 0) found = combo;
            }
            if (l == 0) {
                flag[1] = found;
                flag[2] = (found >= 0 && ((found >> 2) & 3) >= 2) ? 1 : 0;
            }
        }
        if (tid == 0) flag[0] = isbf;
    }
}

// ---- kernel 2: conv1d as f64 GEMM; depth-4 unrolled pipeline + fused BN partials ----
template <typename YT>
__global__ __launch_bounds__(256, 4) void k_conv2(const void* __restrict__ x,
                                                  const void* __restrict__ bias,
                                                  const int* __restrict__ flag,
                                                  const double* __restrict__ wt,
                                                  YT* __restrict__ y,
                                                  double* __restrict__ ps,
                                                  double* __restrict__ pq) {
    __shared__ __align__(16) double xs[CIN * (TT + 2)];  // xs[ci*18 + tl], tl0 = t0-1
    const int isbf = flag[0];
    const int tb = blockIdx.x;
    const int b  = blockIdx.y;
    const int t0 = tb * TT;

    for (int idx = threadIdx.x; idx < CIN * (TT + 2); idx += 256) {
        int tl = idx / CIN;
        int ci = idx - tl * CIN;
        int tg = t0 - 1 + tl;
        double v = 0.0;
        if (tg >= 0 && tg < T_DIM) v = ld_in(x, (b * T_DIM + tg) * CIN + ci, isbf);
        xs[ci * (TT + 2) + tl] = v;
    }
    __syncthreads();

    const int combo = flag[1];
    const int blk = b * NTB + tb;
    const int h = threadIdx.x;

    if (combo >= 0) {
        // ---------- MFMA path: D[t][h] = sum_k A[t][k]*B[k][h] ----------
        const int wave = threadIdx.x >> 6;
        const int lane = threadIdx.x & 63;
        const int h0w  = wave * 64;
        int ai, ak, bk, bj, di[4], dj[4];
        combo_maps(combo, lane, ai, ak, bk, bj, di, dj);

        d4 acc[4];
#pragma unroll
        for (int ht = 0; ht < 4; ht++) { acc[ht][0] = 0.0; acc[ht][1] = 0.0; acc[ht][2] = 0.0; acc[ht][3] = 0.0; }

        // depth-4 software pipeline; #pragma unroll 4 keeps stage index constant
        double aq[4];
        double bq[4][4];
#pragma unroll
        for (int s = 0; s < 4; s++) {
            const int ka = s * 4 + ak;
            const int ca = ka / 3, da = ka - 3 * ca;
            aq[s] = xs[ca * (TT + 2) + ai + da];
            const double* wr = wt + (size_t)(s * 4 + bk) * H_DIM + h0w + bj;
#pragma unroll
            for (int ht = 0; ht < 4; ht++) bq[s][ht] = wr[ht * 16];
        }

#pragma unroll 4
        for (int kk = 0; kk < NKK; kk++) {
            const int st = kk & 3;           // constant after unroll-4
            const double a_c = aq[st];
            double b_c[4];
#pragma unroll
            for (int ht = 0; ht < 4; ht++) b_c[ht] = bq[st][ht];
            if (kk + 4 < NKK) {              // refill stage st for kk+4
                const int ka = (kk + 4) * 4 + ak;
                const int ca = ka / 3, da = ka - 3 * ca;
                aq[st] = xs[ca * (TT + 2) + ai + da];
                const double* wr = wt + (size_t)((kk + 4) * 4 + bk) * H_DIM + h0w + bj;
#pragma unroll
                for (int ht = 0; ht < 4; ht++) bq[st][ht] = wr[ht * 16];
            }
#pragma unroll
            for (int ht = 0; ht < 4; ht++)
                acc[ht] = __builtin_amdgcn_mfma_f64_16x16x4f64(a_c, b_c[ht], acc[ht], 0, 0, 0);
        }

        // ---------- epilogue: bias + direct Y stores + fused BN partials (no LDS) ----------
        const int dc = (combo >> 2) & 3;
        if (dc < 2) {
            // dj[r] = lane&15 (constant per lane) -> per-h bias & shuffle reduction
#pragma unroll
            for (int ht = 0; ht < 4; ht++) {
                const double bv = ld_in(bias, h0w + ht * 16 + (lane & 15), isbf);
                double s1 = 0.0, s2 = 0.0;
#pragma unroll
                for (int r = 0; r < 4; r++) {
                    double v = acc[ht][r] + bv;
                    y[((size_t)(t0 + di[r]) * B_DIM + b) * H_DIM + h0w + ht * 16 + dj[r]] = (YT)v;
                    s1 += v;
                    s2 = fma(v, v, s2);
                }
                // combine the 4 t-row groups (lanes differing in bits 4-5)
                s1 += __shfl_xor(s1, 16); s1 += __shfl_xor(s1, 32);
                s2 += __shfl_xor(s2, 16); s2 += __shfl_xor(s2, 32);
                if ((lane >> 4) == 0) {
                    ps[(size_t)blk * H_DIM + h0w + ht * 16 + lane] = s1;
                    pq[(size_t)blk * H_DIM + h0w + ht * 16 + lane] = s2;
                }
            }
        } else {
            // rare layout: store Y only; stats computed from Y (flag[2]=1)
#pragma unroll
            for (int ht = 0; ht < 4; ht++)
#pragma unroll
                for (int r = 0; r < 4; r++) {
                    const int hh = h0w + ht * 16 + dj[r];
                    double v = acc[ht][r] + ld_in(bias, hh, isbf);
                    y[((size_t)(t0 + di[r]) * B_DIM + b) * H_DIM + hh] = (YT)v;
                }
        }
    } else {
        // ---------- fallback: R5's LDS-staged VALU conv ----------
        double acc[TT];
        const double bv = ld_in(bias, h, isbf);
#pragma unroll
        for (int i = 0; i < TT; i++) acc[i] = bv;

        const double* wp = wt + h;
        double w0 = wp[0], w1 = wp[H_DIM], w2 = wp[2 * H_DIM];
        for (int ci = 0; ci < CIN; ci++) {
            double wn0 = 0.0, wn1 = 0.0, wn2 = 0.0;
            if (ci + 1 < CIN) {
                const double* wq = wt + (size_t)(ci + 1) * 3 * H_DIM + h;
                wn0 = wq[0]; wn1 = wq[H_DIM]; wn2 = wq[2 * H_DIM];
            }
            const double* xr = xs + ci * (TT + 2);
            double x0 = xr[0], x1 = xr[1];
#pragma unroll
            for (int tt = 0; tt < TT; tt += 2) {
                double2 xp = *(const double2*)(xr + tt + 2);
                acc[tt]     = fma(w2, xp.x, fma(w1, x1,   fma(w0, x0, acc[tt])));
                acc[tt + 1] = fma(w2, xp.y, fma(w1, xp.x, fma(w0, x1, acc[tt + 1])));
                x0 = xp.x; x1 = xp.y;
            }
            w0 = wn0; w1 = wn1; w2 = wn2;
        }

        double s1 = 0.0, s2 = 0.0;
#pragma unroll
        for (int tt = 0; tt < TT; tt++) {
            y[((size_t)(t0 + tt) * B_DIM + b) * H_DIM + h] = (YT)acc[tt];
            s1 += acc[tt];
            s2 = fma(acc[tt], acc[tt], s2);
        }
        ps[(size_t)blk * H_DIM + h] = s1;
        pq[(size_t)blk * H_DIM + h] = s2;
    }
}

// ---- kernel 3a: partial BN reduce (mode 0: PS/PQ; mode 1: from Y) ----
template <typename YT>
__global__ __launch_bounds__(256) void k_statsA(const YT* __restrict__ y,
                                                double* __restrict__ ps,
                                                double* __restrict__ pq,
                                                double* __restrict__ pa,
                                                double* __restrict__ pb,
                                                const int* __restrict__ flag) {
    const int h = threadIdx.x;
    if (flag[2]) {
        const int p = blockIdx.x;
        const int tp0 = p * TPY;
        double s1 = 0.0, s2 = 0.0;
        for (int row = 0; row < TPY * B_DIM; row++) {
            int t = tp0 + (row >> 5);
            int bb = row & 31;
            double v = (double)y[((size_t)t * B_DIM + bb) * H_DIM + h];
            s1 += v;
            s2 = fma(v, v, s2);
        }
        ps[(size_t)p * H_DIM + h] = s1;
        pq[(size_t)p * H_DIM + h] = s2;
    } else {
        if (blockIdx.x >= NPART) return;
        const int k = blockIdx.x;
        double s1 = 0.0, s2 = 0.0;
        const int j0 = k * JPER;
        for (int j = j0; j < j0 + JPER; j++) {
            s1 += ps[(size_t)j * H_DIM + h];
            s2 += pq[(size_t)j * H_DIM + h];
        }
        pa[(size_t)k * H_DIM + h] = s1;
        pb[(size_t)k * H_DIM + h] = s2;
    }
}

// ---- kernel 3b: final reduce + fold BN affine ----
__global__ __launch_bounds__(256) void k_statsB(const double* __restrict__ ps,
                                                const double* __restrict__ pq,
                                                const double* __restrict__ pa,
                                                const double* __restrict__ pb,
                                                const void* __restrict__ gamma,
                                                const void* __restrict__ beta,
                                                const int* __restrict__ flag,
                                                double* __restrict__ par) {
    const int isbf = flag[0];
    const int h = threadIdx.x;
    double s1 = 0.0, s2 = 0.0;
    if (flag[2]) {
        for (int k = 0; k < NPY; k++) {
            s1 += ps[(size_t)k * H_DIM + h];
            s2 += pq[(size_t)k * H_DIM + h];
        }
    } else {
        for (int k = 0; k < NPART; k++) {
            s1 += pa[(size_t)k * H_DIM + h];
            s2 += pb[(size_t)k * H_DIM + h];
        }
    }
    const double N = (double)T_DIM * (double)B_DIM;
    double mean = s1 / N;
    double var  = s2 / N - mean * mean;
    double r    = 1.0 / sqrt(var + 1e-5);
    par[h]       = mean;
    par[256 + h] = r * ld_in(gamma, h, isbf);
    par[512 + h] = ld_in(beta, h, isbf);
}

// ---- kernel 4: chunked LIF, LDS double-buffered segments ----
template <typename YT>
__global__ __launch_bounds__(256, 4) void k_lif(const YT* __restrict__ y,
                                                const double* __restrict__ par,
                                                const int* __restrict__ flag,
                                                void* __restrict__ out) {
    __shared__ YT buf[2][SEG * H_DIM];   // 2 x 16 KB (f64)
    const int isbf = flag[0];
    const int c = blockIdx.x, b = blockIdx.y, h = threadIdx.x;
    const int t_out = c * CLEN;
    int t_begin = t_out - WARM; if (t_begin < 0) t_begin = 0;
    const int t_end = t_out + CLEN;
    const int nseg = (t_end - t_begin) / SEG;

    const double m  = par[h];
    const double A  = par[256 + h];
    const double be = par[512 + h];

    const size_t ST = (size_t)B_DIM * H_DIM;
    const YT* yb = y + (size_t)b * H_DIM + h;
    u16*   ob16 = (u16*)out + (size_t)b * H_DIM + h;
    float* ob32 = (float*)out + (size_t)b * H_DIM + h;

    {
        YT g[SEG];
#pragma unroll
        for (int k = 0; k < SEG; k++) g[k] = yb[(size_t)(t_begin + k) * ST];
#pragma unroll
        for (int k = 0; k < SEG; k++) buf[0][k * H_DIM + h] = g[k];
    }
    __syncthreads();

    double v = 0.0;
    for (int s = 0; s < nseg; s++) {
        const int cur = s & 1;
        const bool more = (s + 1 < nseg);
        YT g[SEG];
        if (more) {
            const int t1 = t_begin + (s + 1) * SEG;
#pragma unroll
            for (int k = 0; k < SEG; k++) g[k] = yb[(size_t)(t1 + k) * ST];
        }
        double r[SEG];
#pragma unroll
        for (int k = 0; k < SEG; k++) r[k] = (double)buf[cur][k * H_DIM + h];
        const int t0s = t_begin + s * SEG;
#pragma unroll
        for (int k = 0; k < SEG; k++) {
            double val = fma(r[k] - m, A, be);
            v = fma(v, 0.5, val);
            bool sp = (v - 1.0) >= 0.0;
            const int t = t0s + k;
            if (t >= t_out) {
                size_t oi = (size_t)t * ST;
                if (isbf) ob16[oi] = sp ? (u16)0x3F80 : (u16)0;
                else      ob32[oi] = sp ? 1.0f : 0.0f;
            }
            v = sp ? 0.0 : v;
        }
        if (more) {
#pragma unroll
            for (int k = 0; k < SEG; k++) buf[cur ^ 1][k * H_DIM + h] = g[k];
        }
        __syncthreads();
    }
}

// ---- diagnostic: ws too small ----
__global__ void k_code(u16* out, float code) {
    if (threadIdx.x == 0 && blockIdx.x == 0) {
        union { unsigned int i; float f; } cv; cv.f = code;
        out[0] = (u16)(cv.i >> 16);
    }
}

extern "C" void kernel_launch(void* const* d_in, const int* in_sizes, int n_in,
                              void* d_out, int out_size, void* d_ws, size_t ws_size,
                              hipStream_t stream) {
    const void* x     = d_in[0];
    const void* w     = d_in[1];
    const void* cb    = d_in[2];
    const void* gamma = d_in[3];
    const void* beta  = d_in[4];

    char* wsb   = (char*)d_ws;
    int* flag   = (int*)wsb;
    double* PS  = (double*)(wsb + PS_OFF);
    double* PQ  = (double*)(wsb + PQ_OFF);
    double* PAR = (double*)(wsb + PAR_OFF);
    double* WT  = (double*)(wsb + WT_OFF);
    double* PA  = (double*)(wsb + PA_OFF);
    double* PB  = (double*)(wsb + PB_OFF);
    void* Yp    = (void*)(wsb + Y_OFF);

    const size_t need64 = Y_OFF + Y_ELEMS * 8;   // 143,104,064
    const size_t need32 = Y_OFF + Y_ELEMS * 4;

    if (ws_size < need32) {
        hipMemsetAsync(d_out, 0, (size_t)out_size * 2, stream);
        k_code<<<1, 64, 0, stream>>>((u16*)d_out, 1000.0f);
        return;
    }

    k_prep<<<dim3(241), dim3(256), 0, stream>>>((const u16*)x, w, flag, WT);

    if (ws_size >= need64) {
        k_conv2<double><<<dim3(NTB, B_DIM), dim3(256), 0, stream>>>(
            x, cb, flag, WT, (double*)Yp, PS, PQ);
        k_statsA<double><<<dim3(NPY), dim3(256), 0, stream>>>(
            (const double*)Yp, PS, PQ, PA, PB, flag);
        k_statsB<<<dim3(1), dim3(256), 0, stream>>>(PS, PQ, PA, PB, gamma, beta, flag, PAR);
        k_lif<double><<<dim3(CHUNKS, B_DIM), dim3(256), 0, stream>>>(
            (const double*)Yp, PAR, flag, d_out);
    } else {
        k_conv2<float><<<dim3(NTB, B_DIM), dim3(256), 0, stream>>>(
            x, cb, flag, WT, (float*)Yp, PS, PQ);
        k_statsA<float><<<dim3(NPY), dim3(256), 0, stream>>>(
            (const float*)Yp, PS, PQ, PA, PB, flag);
        k_statsB<<<dim3(1), dim3(256), 0, stream>>>(PS, PQ, PA, PB, gamma, beta, flag, PAR);
        k_lif<float><<<dim3(CHUNKS, B_DIM), dim3(256), 0, stream>>>(
            (const float*)Yp, PAR, flag, d_out);
    }
}

// Round 12
// 294.055 us; speedup vs baseline: 1.5016x; 1.0940x over previous
//
#include <hip/hip_runtime.h>
#include <hip/hip_bf16.h>

#define T_DIM 2048
#define B_DIM 32
#define CIN   80
#define H_DIM 256
#define TT    16               // t-tile per conv block
#define NTB   (T_DIM / TT)     // 128
#define NBLK  (B_DIM * NTB)    // 4096 conv blocks
#define KTOT  (CIN * 3)        // 240
#define NKK   (KTOT / 4)       // 60 MFMA K-steps

// LIF chunking (warm-up resync; verified absmax=0 in R3-R11)
#define CHUNKS 32
#define CLEN  (T_DIM / CHUNKS) // 64
#define WARM  48
#define SEG   8

#define NPART 64
#define JPER  (NBLK / NPART)   // 64
#define NPY   256              // from-Y stats partials (fallback mode)
#define TPY   (T_DIM / NPY)    // 8

typedef unsigned short u16;
typedef __attribute__((ext_vector_type(4))) double d4;

// ---- workspace byte offsets ----
// flag[0]=isbf, flag[1]=mfma combo id (-1 = VALU fallback), flag[2]=stats-from-Y mode
#define PS_OFF  ((size_t)64)
#define PQ_OFF  (PS_OFF + (size_t)NBLK * H_DIM * 8)
#define PAR_OFF (PQ_OFF + (size_t)NBLK * H_DIM * 8)
#define WT_OFF  (PAR_OFF + (size_t)768 * 8)
#define PA_OFF  WT_OFF                                  // alias WT (dead after conv)
#define PB_OFF  (WT_OFF + (size_t)NPART * H_DIM * 8)
#define Y_OFF   (WT_OFF + (size_t)H_DIM * CIN * 3 * 8)
#define Y_ELEMS ((size_t)T_DIM * B_DIM * H_DIM)         // 16,777,216

__device__ __forceinline__ double bf2d(u16 u) {
    union { unsigned int i; float f; } cv;
    cv.i = ((unsigned int)u) << 16;
    return (double)cv.f;
}

__device__ __forceinline__ double ld_in(const void* p, int i, int isbf) {
    if (isbf) return bf2d(((const u16*)p)[i]);
    return (double)((const float*)p)[i];
}

// candidate lane->fragment index maps
__device__ __forceinline__ void combo_maps(int combo, int l,
                                           int& ai, int& ak, int& bk, int& bj,
                                           int di[4], int dj[4]) {
    if (combo & 1) { ai = l >> 2; ak = l & 3; } else { ai = l & 15; ak = l >> 4; }
    if (combo & 2) { bk = l & 3; bj = l >> 2; } else { bk = l >> 4; bj = l & 15; }
    const int dc = (combo >> 2) & 3;
#pragma unroll
    for (int r = 0; r < 4; r++) {
        if (dc == 0)      { di[r] = 4 * (l >> 4) + r; dj[r] = l & 15; }
        else if (dc == 1) { di[r] = (l >> 4) + 4 * r; dj[r] = l & 15; }
        else if (dc == 2) { di[r] = l & 15; dj[r] = 4 * (l >> 4) + r; }
        else              { di[r] = l & 15; dj[r] = (l >> 4) + 4 * r; }
    }
}

// ---- kernel 0 (merged prep): dtype detect + w transpose + (block 240) layout probe ----
__global__ __launch_bounds__(256) void k_prep(const u16* __restrict__ xu,
                                              const void* __restrict__ w,
                                              int* __restrict__ flag,
                                              double* __restrict__ wt) {
    __shared__ int cnt[256];
    __shared__ int isbf_s;
    const int tid = threadIdx.x;
    int c = 0;
    for (int j = 0; j < 8; j++) {
        u16 u = xu[tid * 8 + j];
        int e = (u >> 7) & 0xFF;
        if ((u & 0x7FFF) == 0 || (e >= 97 && e <= 157)) c++;
    }
    cnt[tid] = c;
    __syncthreads();
    for (int off = 128; off > 0; off >>= 1) {
        if (tid < off) cnt[tid] += cnt[tid + off];
        __syncthreads();
    }
    if (tid == 0) isbf_s = (cnt[0] >= 1639) ? 1 : 0;
    __syncthreads();
    const int isbf = isbf_s;

    if (blockIdx.x < 240) {
        int idx = blockIdx.x * 256 + tid;        // < 61440 = H*CIN*3
        int h = idx / KTOT;
        int r = idx - h * KTOT;
        wt[(size_t)r * H_DIM + h] = ld_in(w, idx, isbf);
    } else {
        if (tid < 64) {
            const int l = tid;
            int found = -1;
            for (int combo = 0; combo < 16; combo++) {
                int ai, ak, bk, bj, di[4], dj[4];
                combo_maps(combo, l, ai, ak, bk, bj, di, dj);
                double a = (double)(ai * 4 + ak + 1);
                double b = (double)(bk * 16 + bj + 1);
                d4 cc;
#pragma unroll
                for (int r = 0; r < 4; r++) cc[r] = (double)(di[r] * 16 + dj[r]);
                d4 d = __builtin_amdgcn_mfma_f64_16x16x4f64(a, b, cc, 0, 0, 0);
                bool ok = true;
#pragma unroll
                for (int r = 0; r < 4; r++) {
                    double ref = (double)(di[r] * 16 + dj[r]);
                    for (int k = 0; k < 4; k++)
                        ref += (double)(di[r] * 4 + k + 1) * (double)(k * 16 + dj[r] + 1);
                    if (d[r] != ref) ok = false;
                }
                if (__all(ok) && found < 0) found = combo;
            }
            if (l == 0) {
                flag[1] = found;
                flag[2] = (found >= 0 && ((found >> 2) & 3) >= 2) ? 1 : 0;
            }
        }
        if (tid == 0) flag[0] = isbf;
    }
}

// ---- kernel 2: conv1d as f64 GEMM; DUAL-PIPE: even tb -> MFMA, odd tb -> VALU ----
template <typename YT>
__global__ __launch_bounds__(256, 4) void k_conv2(const void* __restrict__ x,
                                                  const void* __restrict__ bias,
                                                  const int* __restrict__ flag,
                                                  const double* __restrict__ wt,
                                                  YT* __restrict__ y,
                                                  double* __restrict__ ps,
                                                  double* __restrict__ pq) {
    __shared__ __align__(16) double xs[CIN * (TT + 2)];  // xs[ci*18 + tl], tl0 = t0-1
    const int isbf = flag[0];
    const int tb = blockIdx.x;
    const int b  = blockIdx.y;
    const int t0 = tb * TT;

    for (int idx = threadIdx.x; idx < CIN * (TT + 2); idx += 256) {
        int tl = idx / CIN;
        int ci = idx - tl * CIN;
        int tg = t0 - 1 + tl;
        double v = 0.0;
        if (tg >= 0 && tg < T_DIM) v = ld_in(x, (b * T_DIM + tg) * CIN + ci, isbf);
        xs[ci * (TT + 2) + tl] = v;
    }
    __syncthreads();

    const int combo = flag[1];
    const int blk = b * NTB + tb;
    const int h = threadIdx.x;

    // dual-pipe split: matrix pipe and vector pipe co-schedule on a CU (m114)
    if (combo >= 0 && (tb & 1) == 0) {
        // ---------- MFMA path (R8's 1-deep prefetch: VGPR-lean, occupancy-first) ----------
        const int wave = threadIdx.x >> 6;
        const int lane = threadIdx.x & 63;
        const int h0w  = wave * 64;
        int ai, ak, bk, bj, di[4], dj[4];
        combo_maps(combo, lane, ai, ak, bk, bj, di, dj);

        d4 acc[4];
#pragma unroll
        for (int ht = 0; ht < 4; ht++) { acc[ht][0] = 0.0; acc[ht][1] = 0.0; acc[ht][2] = 0.0; acc[ht][3] = 0.0; }

        // 1-deep software pipeline on A (LDS) and B (global/L2) operands
        int ca0 = ak / 3, da0 = ak - 3 * ca0;
        double a_cur = xs[ca0 * (TT + 2) + ai + da0];
        double b_cur[4];
        {
            const double* wr = wt + (size_t)bk * H_DIM + h0w + bj;
#pragma unroll
            for (int ht = 0; ht < 4; ht++) b_cur[ht] = wr[ht * 16];
        }

        for (int kk = 0; kk < NKK; kk++) {
            double a_nxt = 0.0, b_nxt[4] = {0.0, 0.0, 0.0, 0.0};
            if (kk + 1 < NKK) {
                const int kan = (kk + 1) * 4 + ak;
                const int cin = kan / 3, dkn = kan - 3 * cin;
                a_nxt = xs[cin * (TT + 2) + ai + dkn];
                const double* wr = wt + (size_t)((kk + 1) * 4 + bk) * H_DIM + h0w + bj;
#pragma unroll
                for (int ht = 0; ht < 4; ht++) b_nxt[ht] = wr[ht * 16];
            }
#pragma unroll
            for (int ht = 0; ht < 4; ht++)
                acc[ht] = __builtin_amdgcn_mfma_f64_16x16x4f64(a_cur, b_cur[ht], acc[ht], 0, 0, 0);
            a_cur = a_nxt;
#pragma unroll
            for (int ht = 0; ht < 4; ht++) b_cur[ht] = b_nxt[ht];
        }

        // ---------- epilogue: bias + direct Y stores + fused BN partials (no LDS) ----------
        const int dc = (combo >> 2) & 3;
        if (dc < 2) {
#pragma unroll
            for (int ht = 0; ht < 4; ht++) {
                const double bv = ld_in(bias, h0w + ht * 16 + (lane & 15), isbf);
                double s1 = 0.0, s2 = 0.0;
#pragma unroll
                for (int r = 0; r < 4; r++) {
                    double v = acc[ht][r] + bv;
                    y[((size_t)(t0 + di[r]) * B_DIM + b) * H_DIM + h0w + ht * 16 + dj[r]] = (YT)v;
                    s1 += v;
                    s2 = fma(v, v, s2);
                }
                s1 += __shfl_xor(s1, 16); s1 += __shfl_xor(s1, 32);
                s2 += __shfl_xor(s2, 16); s2 += __shfl_xor(s2, 32);
                if ((lane >> 4) == 0) {
                    ps[(size_t)blk * H_DIM + h0w + ht * 16 + lane] = s1;
                    pq[(size_t)blk * H_DIM + h0w + ht * 16 + lane] = s2;
                }
            }
        } else {
            // rare layout: store Y only; stats computed from Y (flag[2]=1)
#pragma unroll
            for (int ht = 0; ht < 4; ht++)
#pragma unroll
                for (int r = 0; r < 4; r++) {
                    const int hh = h0w + ht * 16 + dj[r];
                    double v = acc[ht][r] + ld_in(bias, hh, isbf);
                    y[((size_t)(t0 + di[r]) * B_DIM + b) * H_DIM + hh] = (YT)v;
                }
        }
    } else {
        // ---------- VALU path (R5's LDS-staged conv, vector pipe) ----------
        double acc[TT];
        const double bv = ld_in(bias, h, isbf);
#pragma unroll
        for (int i = 0; i < TT; i++) acc[i] = bv;

        const double* wp = wt + h;
        double w0 = wp[0], w1 = wp[H_DIM], w2 = wp[2 * H_DIM];
        for (int ci = 0; ci < CIN; ci++) {
            double wn0 = 0.0, wn1 = 0.0, wn2 = 0.0;
            if (ci + 1 < CIN) {
                const double* wq = wt + (size_t)(ci + 1) * 3 * H_DIM + h;
                wn0 = wq[0]; wn1 = wq[H_DIM]; wn2 = wq[2 * H_DIM];
            }
            const double* xr = xs + ci * (TT + 2);
            double x0 = xr[0], x1 = xr[1];
#pragma unroll
            for (int tt = 0; tt < TT; tt += 2) {
                double2 xp = *(const double2*)(xr + tt + 2);
                acc[tt]     = fma(w2, xp.x, fma(w1, x1,   fma(w0, x0, acc[tt])));
                acc[tt + 1] = fma(w2, xp.y, fma(w1, xp.x, fma(w0, x1, acc[tt + 1])));
                x0 = xp.x; x1 = xp.y;
            }
            w0 = wn0; w1 = wn1; w2 = wn2;
        }

        double s1 = 0.0, s2 = 0.0;
#pragma unroll
        for (int tt = 0; tt < TT; tt++) {
            y[((size_t)(t0 + tt) * B_DIM + b) * H_DIM + h] = (YT)acc[tt];
            s1 += acc[tt];
            s2 = fma(acc[tt], acc[tt], s2);
        }
        ps[(size_t)blk * H_DIM + h] = s1;
        pq[(size_t)blk * H_DIM + h] = s2;
    }
}

// ---- kernel 3a: partial BN reduce (mode 0: PS/PQ; mode 1: from Y) ----
template <typename YT>
__global__ __launch_bounds__(256) void k_statsA(const YT* __restrict__ y,
                                                double* __restrict__ ps,
                                                double* __restrict__ pq,
                                                double* __restrict__ pa,
                                                double* __restrict__ pb,
                                                const int* __restrict__ flag) {
    const int h = threadIdx.x;
    if (flag[2]) {
        const int p = blockIdx.x;
        const int tp0 = p * TPY;
        double s1 = 0.0, s2 = 0.0;
        for (int row = 0; row < TPY * B_DIM; row++) {
            int t = tp0 + (row >> 5);
            int bb = row & 31;
            double v = (double)y[((size_t)t * B_DIM + bb) * H_DIM + h];
            s1 += v;
            s2 = fma(v, v, s2);
        }
        ps[(size_t)p * H_DIM + h] = s1;
        pq[(size_t)p * H_DIM + h] = s2;
    } else {
        if (blockIdx.x >= NPART) return;
        const int k = blockIdx.x;
        double s1 = 0.0, s2 = 0.0;
        const int j0 = k * JPER;
        for (int j = j0; j < j0 + JPER; j++) {
            s1 += ps[(size_t)j * H_DIM + h];
            s2 += pq[(size_t)j * H_DIM + h];
        }
        pa[(size_t)k * H_DIM + h] = s1;
        pb[(size_t)k * H_DIM + h] = s2;
    }
}

// ---- kernel 3b: final reduce + fold BN affine ----
__global__ __launch_bounds__(256) void k_statsB(const double* __restrict__ ps,
                                                const double* __restrict__ pq,
                                                const double* __restrict__ pa,
                                                const double* __restrict__ pb,
                                                const void* __restrict__ gamma,
                                                const void* __restrict__ beta,
                                                const int* __restrict__ flag,
                                                double* __restrict__ par) {
    const int isbf = flag[0];
    const int h = threadIdx.x;
    double s1 = 0.0, s2 = 0.0;
    if (flag[2]) {
        for (int k = 0; k < NPY; k++) {
            s1 += ps[(size_t)k * H_DIM + h];
            s2 += pq[(size_t)k * H_DIM + h];
        }
    } else {
        for (int k = 0; k < NPART; k++) {
            s1 += pa[(size_t)k * H_DIM + h];
            s2 += pb[(size_t)k * H_DIM + h];
        }
    }
    const double N = (double)T_DIM * (double)B_DIM;
    double mean = s1 / N;
    double var  = s2 / N - mean * mean;
    double r    = 1.0 / sqrt(var + 1e-5);
    par[h]       = mean;
    par[256 + h] = r * ld_in(gamma, h, isbf);
    par[512 + h] = ld_in(beta, h, isbf);
}

// ---- kernel 4: chunked LIF, LDS double-buffered segments ----
template <typename YT>
__global__ __launch_bounds__(256, 4) void k_lif(const YT* __restrict__ y,
                                                const double* __restrict__ par,
                                                const int* __restrict__ flag,
                                                void* __restrict__ out) {
    __shared__ YT buf[2][SEG * H_DIM];   // 2 x 16 KB (f64)
    const int isbf = flag[0];
    const int c = blockIdx.x, b = blockIdx.y, h = threadIdx.x;
    const int t_out = c * CLEN;
    int t_begin = t_out - WARM; if (t_begin < 0) t_begin = 0;
    const int t_end = t_out + CLEN;
    const int nseg = (t_end - t_begin) / SEG;

    const double m  = par[h];
    const double A  = par[256 + h];
    const double be = par[512 + h];

    const size_t ST = (size_t)B_DIM * H_DIM;
    const YT* yb = y + (size_t)b * H_DIM + h;
    u16*   ob16 = (u16*)out + (size_t)b * H_DIM + h;
    float* ob32 = (float*)out + (size_t)b * H_DIM + h;

    {
        YT g[SEG];
#pragma unroll
        for (int k = 0; k < SEG; k++) g[k] = yb[(size_t)(t_begin + k) * ST];
#pragma unroll
        for (int k = 0; k < SEG; k++) buf[0][k * H_DIM + h] = g[k];
    }
    __syncthreads();

    double v = 0.0;
    for (int s = 0; s < nseg; s++) {
        const int cur = s & 1;
        const bool more = (s + 1 < nseg);
        YT g[SEG];
        if (more) {
            const int t1 = t_begin + (s + 1) * SEG;
#pragma unroll
            for (int k = 0; k < SEG; k++) g[k] = yb[(size_t)(t1 + k) * ST];
        }
        double r[SEG];
#pragma unroll
        for (int k = 0; k < SEG; k++) r[k] = (double)buf[cur][k * H_DIM + h];
        const int t0s = t_begin + s * SEG;
#pragma unroll
        for (int k = 0; k < SEG; k++) {
            double val = fma(r[k] - m, A, be);
            v = fma(v, 0.5, val);
            bool sp = (v - 1.0) >= 0.0;
            const int t = t0s + k;
            if (t >= t_out) {
                size_t oi = (size_t)t * ST;
                if (isbf) ob16[oi] = sp ? (u16)0x3F80 : (u16)0;
                else      ob32[oi] = sp ? 1.0f : 0.0f;
            }
            v = sp ? 0.0 : v;
        }
        if (more) {
#pragma unroll
            for (int k = 0; k < SEG; k++) buf[cur ^ 1][k * H_DIM + h] = g[k];
        }
        __syncthreads();
    }
}

// ---- diagnostic: ws too small ----
__global__ void k_code(u16* out, float code) {
    if (threadIdx.x == 0 && blockIdx.x == 0) {
        union { unsigned int i; float f; } cv; cv.f = code;
        out[0] = (u16)(cv.i >> 16);
    }
}

extern "C" void kernel_launch(void* const* d_in, const int* in_sizes, int n_in,
                              void* d_out, int out_size, void* d_ws, size_t ws_size,
                              hipStream_t stream) {
    const void* x     = d_in[0];
    const void* w     = d_in[1];
    const void* cb    = d_in[2];
    const void* gamma = d_in[3];
    const void* beta  = d_in[4];

    char* wsb   = (char*)d_ws;
    int* flag   = (int*)wsb;
    double* PS  = (double*)(wsb + PS_OFF);
    double* PQ  = (double*)(wsb + PQ_OFF);
    double* PAR = (double*)(wsb + PAR_OFF);
    double* WT  = (double*)(wsb + WT_OFF);
    double* PA  = (double*)(wsb + PA_OFF);
    double* PB  = (double*)(wsb + PB_OFF);
    void* Yp    = (void*)(wsb + Y_OFF);

    const size_t need64 = Y_OFF + Y_ELEMS * 8;   // 143,104,064
    const size_t need32 = Y_OFF + Y_ELEMS * 4;

    if (ws_size < need32) {
        hipMemsetAsync(d_out, 0, (size_t)out_size * 2, stream);
        k_code<<<1, 64, 0, stream>>>((u16*)d_out, 1000.0f);
        return;
    }

    k_prep<<<dim3(241), dim3(256), 0, stream>>>((const u16*)x, w, flag, WT);

    if (ws_size >= need64) {
        k_conv2<double><<<dim3(NTB, B_DIM), dim3(256), 0, stream>>>(
            x, cb, flag, WT, (double*)Yp, PS, PQ);
        k_statsA<double><<<dim3(NPY), dim3(256), 0, stream>>>(
            (const double*)Yp, PS, PQ, PA, PB, flag);
        k_statsB<<<dim3(1), dim3(256), 0, stream>>>(PS, PQ, PA, PB, gamma, beta, flag, PAR);
        k_lif<double><<<dim3(CHUNKS, B_DIM), dim3(256), 0, stream>>>(
            (const double*)Yp, PAR, flag, d_out);
    } else {
        k_conv2<float><<<dim3(NTB, B_DIM), dim3(256), 0, stream>>>(
            x, cb, flag, WT, (float*)Yp, PS, PQ);
        k_statsA<float><<<dim3(NPY), dim3(256), 0, stream>>>(
            (const float*)Yp, PS, PQ, PA, PB, flag);
        k_statsB<<<dim3(1), dim3(256), 0, stream>>>(PS, PQ, PA, PB, gamma, beta, flag, PAR);
        k_lif<float><<<dim3(CHUNKS, B_DIM), dim3(256), 0, stream>>>(
            (const float*)Yp, PAR, flag, d_out);
    }
}